// Round 12
// baseline (93.504 us; speedup 1.0000x reference)
//
#include <hip/hip_runtime.h>
#include <stdint.h>

// Problem constants
#define B_ 2
#define S_ 2048
#define H_ 1024
#define NH_ 16
#define HD_ 64
#define M_ 4096            // B*S
#define LOG2E 1.44269504089f

typedef unsigned short u16;
typedef __bf16 bf16x8 __attribute__((ext_vector_type(8)));
typedef float  f32x4  __attribute__((ext_vector_type(4)));

#if __has_builtin(__builtin_amdgcn_exp2f)
#define EXP2(x) __builtin_amdgcn_exp2f(x)
#else
#define EXP2(x) exp2f(x)
#endif

#define WAITV4() asm volatile("s_waitcnt vmcnt(4)" ::: "memory")
#define WAITV0() asm volatile("s_waitcnt vmcnt(0)" ::: "memory")
#define SCHED0() __builtin_amdgcn_sched_barrier(0)

__device__ inline u16 f2bf(float f) {
  union { float f; uint32_t u; } a; a.f = f;
  uint32_t r = a.u + 0x7FFFu + ((a.u >> 16) & 1u);
  return (u16)(r >> 16);
}

__device__ inline void gload_lds16(const void* g, void* l) {
  __builtin_amdgcn_global_load_lds((const __attribute__((address_space(1))) void*)g,
                                   (__attribute__((address_space(3))) void*)l, 16, 0, 0);
}

// ---------------- Kernel 1: f32 -> bf16 convert; W' = W + 4*LB*A folded; mask*log2e ----------------
__global__ __launch_bounds__(256) void cvt_kernel(
    const float* __restrict__ x,
    const float* __restrict__ wq, const float* __restrict__ wk, const float* __restrict__ wv,
    const float* __restrict__ Aq, const float* __restrict__ Ak, const float* __restrict__ Av,
    const float* __restrict__ LBq, const float* __restrict__ LBk, const float* __restrict__ LBv,
    const float* __restrict__ amask,
    u16* __restrict__ xbf, u16* __restrict__ wbf, float* __restrict__ maskl2e) {
  const int XN = M_ * H_;            // 4194304
  const int WN = H_ * H_;            // 1048576
  const int total = XN + 3 * WN;
  int idx = (blockIdx.x * 256 + threadIdx.x) * 4;
  if (idx < XN) {
    float4 v = *(const float4*)(x + idx);
    *(ushort4*)(xbf + idx) = make_ushort4(f2bf(v.x), f2bf(v.y), f2bf(v.z), f2bf(v.w));
  } else if (idx < total) {
    int j = idx - XN; int p = j >> 20; int off = j & (WN - 1);
    const float* W  = (p == 0) ? wq : (p == 1 ? wk : wv);
    const float* A  = (p == 0) ? Aq : (p == 1 ? Ak : Av);
    const float* LB = (p == 0) ? LBq : (p == 1 ? LBk : LBv);
    int n = off >> 10, k = off & 1023;
    float4 v  = *(const float4*)(W + off);
    f32x4 lb  = *(const f32x4*)&LB[n * 4];
    float4 a0 = *(const float4*)(A + k);
    float4 a1 = *(const float4*)(A + 1024 + k);
    float4 a2 = *(const float4*)(A + 2048 + k);
    float4 a3 = *(const float4*)(A + 3072 + k);
    v.x += 4.f * (lb.x * a0.x + lb.y * a1.x + lb.z * a2.x + lb.w * a3.x);
    v.y += 4.f * (lb.x * a0.y + lb.y * a1.y + lb.z * a2.y + lb.w * a3.y);
    v.z += 4.f * (lb.x * a0.z + lb.y * a1.z + lb.z * a2.z + lb.w * a3.z);
    v.w += 4.f * (lb.x * a0.w + lb.y * a1.w + lb.z * a2.w + lb.w * a3.w);
    *(ushort4*)(wbf + (p << 20) + off) = make_ushort4(f2bf(v.x), f2bf(v.y), f2bf(v.z), f2bf(v.w));
  } else {
    int mi = idx - total;                       // 0..4095: B*S mask values, pre-scaled
    if (mi < B_ * S_) {
      float4 mv = *(const float4*)(amask + mi);
      mv.x *= LOG2E; mv.y *= LOG2E; mv.z *= LOG2E; mv.w *= LOG2E;
      *(float4*)(maskl2e + mi) = mv;
    }
  }
}

// ---------------- Kernel 2: fused QKV GEMM, 3-buffer counted-vmcnt pipeline ----------------
template<int P>
__device__ __forceinline__ void gemm_body(
    const u16* __restrict__ xbf, const u16* __restrict__ wbf,
    const float* __restrict__ bias, u16* __restrict__ qkv,
    u16* __restrict__ As, u16* __restrict__ Bs) {
  const int n0 = blockIdx.x * 128;
  const int m0 = blockIdx.y * 128;
  const u16* Wp = wbf + (P << 20);
  const int tid = threadIdx.x, lane = tid & 63, w = tid >> 6;
  const int g = lane >> 4, q15 = lane & 15;
  const int wr = w >> 1, wc = w & 1;
  const f32x4 fzero = {0.f, 0.f, 0.f, 0.f};
  f32x4 acc[4][4];
#pragma unroll
  for (int mi = 0; mi < 4; ++mi)
#pragma unroll
    for (int ni = 0; ni < 4; ++ni) acc[mi][ni] = fzero;
  const int srow = lane >> 2;

  auto STAGE = [&](int buf, int k0) {
#pragma unroll
    for (int j = 0; j < 2; ++j) {
      int c = w * 2 + j;
      int row = c * 16 + srow;
      int uu = (lane & 3) ^ ((row >> 1) & 3);     // pre-swizzled global 16B-unit
      gload_lds16(xbf + (size_t)(m0 + row) * 1024 + k0 + uu * 8, As + buf * 4096 + c * 512);
      gload_lds16(Wp  + (size_t)(n0 + row) * 1024 + k0 + uu * 8, Bs + buf * 4096 + c * 512);
    }
  };

  STAGE(0, 0);
  STAGE(1, 32);
  int c0 = 0, c1 = 1, c2 = 2;
#pragma unroll 1
  for (int t = 0; t < 32; ++t) {
    if (t < 31) WAITV4(); else WAITV0();   // own stage(t) landed; stage(t+1) stays in flight
    SCHED0();
    __builtin_amdgcn_s_barrier();          // all waves' stage(t) landed; buf[c2] reads done
    if (t + 2 < 32) STAGE(c2, (t + 2) * 32);
    const u16* Ab = As + c0 * 4096;
    const u16* Bb = Bs + c0 * 4096;
    bf16x8 af[4], bfr[4];
#pragma unroll
    for (int mi = 0; mi < 4; ++mi) {
      int r = wr * 64 + mi * 16 + q15;
      af[mi] = *(const bf16x8*)&Ab[r * 32 + ((g ^ ((r >> 1) & 3)) * 8)];
    }
#pragma unroll
    for (int ni = 0; ni < 4; ++ni) {
      int r = wc * 64 + ni * 16 + q15;
      bfr[ni] = *(const bf16x8*)&Bb[r * 32 + ((g ^ ((r >> 1) & 3)) * 8)];
    }
    __builtin_amdgcn_s_setprio(1);
#pragma unroll
    for (int mi = 0; mi < 4; ++mi)
#pragma unroll
      for (int ni = 0; ni < 4; ++ni) {
        if (P == 2)
          acc[mi][ni] = __builtin_amdgcn_mfma_f32_16x16x32_bf16(af[mi], bfr[ni], acc[mi][ni], 0, 0, 0);
        else
          acc[mi][ni] = __builtin_amdgcn_mfma_f32_16x16x32_bf16(bfr[ni], af[mi], acc[mi][ni], 0, 0, 0);
      }
    __builtin_amdgcn_s_setprio(0);
    int tmp = c0; c0 = c1; c1 = c2; c2 = tmp;
  }

  // ---- epilogue: bias + vectorized ushort4 stores ----
  if (P != 2) {
#pragma unroll
    for (int ni = 0; ni < 4; ++ni) {
      int nb = n0 + wc * 64 + ni * 16 + g * 4;       // 4-aligned
      f32x4 bi = *(const f32x4*)&bias[nb];
      int h = nb >> 6, dbase = nb & 63;
#pragma unroll
      for (int mi = 0; mi < 4; ++mi) {
        int m = m0 + wr * 64 + mi * 16 + q15;
        int bb = m >> 11, s = m & 2047;
        size_t bhs = (size_t)(bb * 16 + h) * 2048 + s;
        float v0 = acc[mi][ni][0] + bi.x, v1 = acc[mi][ni][1] + bi.y;
        float v2 = acc[mi][ni][2] + bi.z, v3 = acc[mi][ni][3] + bi.w;
        size_t addr;
        if (P == 0) {
          const float qs = 0.125f * LOG2E;           // fold 1/sqrt(HD), log2(e)
          v0 *= qs; v1 *= qs; v2 *= qs; v3 *= qs;
          addr = bhs * 64 + dbase;
        } else {
          int pos = (((dbase >> 3) ^ (s & 7)) << 3) | (dbase & 7);   // K 16B-unit swz
          addr = 4194304 + bhs * 64 + pos;
        }
        *(ushort4*)&qkv[addr] = make_ushort4(f2bf(v0), f2bf(v1), f2bf(v2), f2bf(v3));
      }
    }
  } else {
    float biasv[4];
#pragma unroll
    for (int ni = 0; ni < 4; ++ni) biasv[ni] = bias[n0 + wc * 64 + ni * 16 + q15];
#pragma unroll
    for (int mi = 0; mi < 4; ++mi) {
      int mbase = m0 + wr * 64 + mi * 16 + g * 4;    // r -> consecutive s
      int bb = mbase >> 11, sbase = mbase & 2047;
      int sr = sbase & 31;
      int cba = (((sr >> 4) & 1) << 2) | (((sr >> 2) & 3) << 3);     // P-frag col perm
      int sp = (sbase & 32) | cba;
#pragma unroll
      for (int ni = 0; ni < 4; ++ni) {
        int n = n0 + wc * 64 + ni * 16 + q15;
        int d = n & 63, h = n >> 6;
        int spp = (((sp >> 3) ^ (d & 7)) << 3) | (sp & 7);           // 16B-unit swz
        size_t addr = 8388608 + ((size_t)(bb * 16 + h) * 64 + d) * 2048 + (sbase & ~63) + spp;
        *(ushort4*)&qkv[addr] = make_ushort4(
            f2bf(acc[mi][ni][0] + biasv[ni]), f2bf(acc[mi][ni][1] + biasv[ni]),
            f2bf(acc[mi][ni][2] + biasv[ni]), f2bf(acc[mi][ni][3] + biasv[ni]));
      }
    }
  }
}

__global__ __launch_bounds__(256) void qkv_gemm(
    const u16* __restrict__ xbf, const u16* __restrict__ wbf,
    const float* __restrict__ bq, const float* __restrict__ bk, const float* __restrict__ bv,
    u16* __restrict__ qkv) {
  __shared__ __align__(16) u16 As[3 * 4096];
  __shared__ __align__(16) u16 Bs[3 * 4096];
  switch (blockIdx.z) {
    case 0: gemm_body<0>(xbf, wbf, bq, qkv, As, Bs); break;
    case 1: gemm_body<1>(xbf, wbf, bk, qkv, As, Bs); break;
    default: gemm_body<2>(xbf, wbf, bv, qkv, As, Bs); break;
  }
}

// ---------------- Kernel 3: causal flash attention (R6 shell + K-direct-to-regs) ----------------
// 1024 blocks (one 64-q tile each), long-qt-first, 4 bh per XCD, 4 waves x 16 q.
// K frags are wave-invariant in LDS -> load them global->reg instead (L2-resident,
// swizzle baked in layout, issued right after QK so latency hides under softmax+PV).
// V + mask stay in LDS: 2-buffer V (16 KB) + mask (8 KB) = 24 KB -> 4 blocks/CU.
__global__ __launch_bounds__(256, 4) void attn_kernel(
    const u16* __restrict__ qkv, const float* __restrict__ maskl2e, float* __restrict__ out) {
  const int bid = blockIdx.x;
  const int bh = (bid & 7) * 4 + ((bid >> 3) & 3);   // 4 bh per XCD -> K/V L2-resident
  const int qt = 31 - (bid >> 5);                    // long blocks first
  const int b = bh >> 4, h = bh & 15;
  const int tid = threadIdx.x, lane = tid & 63, w = tid >> 6;
  const int g = lane >> 4, ql = lane & 15, m7 = ql & 7;
  const u16* Qb = qkv + (size_t)bh * 131072;
  const u16* Kb = qkv + 4194304 + (size_t)bh * 131072;
  const u16* Vb = qkv + 8388608 + (size_t)bh * 131072;   // [64][2048] transposed
  __shared__ __align__(16) u16 Vs[2][64][64];
  __shared__ __align__(16) float MaskL[2048];
  const f32x4 fzero = {0.f, 0.f, 0.f, 0.f};

  // one-time mask preload (already *log2e)
  {
    int o = tid * 4;
#pragma unroll
    for (int i = 0; i < 2; ++i)
      *(float4*)&MaskL[o + i * 1024] = *(const float4*)&maskl2e[b * 2048 + o + i * 1024];
  }

  auto STAGEV = [&](int nb, int kb) {
#pragma unroll
    for (int j = 0; j < 2; ++j) {
      int rl = w * 16 + j * 8 + (lane >> 3);
      gload_lds16(Vb + (size_t)rl * 2048 + kb + (lane & 7) * 8, &Vs[nb][w * 16 + j * 8][0]);
    }
  };

  const int qw = qt * 64 + w * 16;
  const int q  = qw + ql;
  bf16x8 qf[2];
#pragma unroll
  for (int ks = 0; ks < 2; ++ks)
    qf[ks] = *(const bf16x8*)&Qb[(size_t)q * 64 + ks * 32 + g * 8];
  f32x4 acc[4];
#pragma unroll
  for (int dt = 0; dt < 4; ++dt) acc[dt] = fzero;
  float mrun = -1e30f, lrun = 0.f;
  const int nt = qt + 1;

  bf16x8 kA[8];
#define LOADK(KT) do { const int kb_ = (KT) * 64; \
  _Pragma("unroll") for (int k16 = 0; k16 < 4; ++k16) { \
    kA[k16*2]   = *(const bf16x8*)&Kb[(size_t)(kb_ + k16*16 + ql) * 64 + ((g ^ m7) * 8)]; \
    kA[k16*2+1] = *(const bf16x8*)&Kb[(size_t)(kb_ + k16*16 + ql) * 64 + (((4 + g) ^ m7) * 8)]; } } while (0)

  STAGEV(0, 0);
  LOADK(0);

#pragma unroll 1
  for (int t = 0; t < nt; ++t) {
    WAITV0();                       // stage_V(t) + K(t) landed
    SCHED0();
    __builtin_amdgcn_s_barrier();   // all waves staged(t); buf[(t+1)&1] V reads done
    const int kb = t * 64;
    if (t + 1 < nt) STAGEV((t + 1) & 1, kb + 64);
    const int cb = t & 1;
    // ---- QK^T: S^T, lane owns q=ql; keys k16*16 + g*4 + r; K from regs ----
    f32x4 st[4];
    __builtin_amdgcn_s_setprio(1);
#pragma unroll
    for (int k16 = 0; k16 < 4; ++k16) {
      st[k16] = __builtin_amdgcn_mfma_f32_16x16x32_bf16(kA[k16*2],   qf[0], fzero,   0, 0, 0);
      st[k16] = __builtin_amdgcn_mfma_f32_16x16x32_bf16(kA[k16*2+1], qf[1], st[k16], 0, 0, 0);
    }
    __builtin_amdgcn_s_setprio(0);
    if (t + 1 < nt) LOADK(t + 1);   // reuse kA; WAR safe (MFMAs issued); hides under softmax+PV
    f32x4 mk[4];
#pragma unroll
    for (int k16 = 0; k16 < 4; ++k16) mk[k16] = *(const f32x4*)&MaskL[kb + k16 * 16 + g * 4];
    // ---- online softmax (log2 domain, defer-max THR=8, max3 tree) ----
    const bool needm = (t == nt - 1);            // diagonal tile only (wave-uniform)
    float sc[16];
#pragma unroll
    for (int k16 = 0; k16 < 4; ++k16)
#pragma unroll
      for (int r = 0; r < 4; ++r) {
        float sv = st[k16][r] + mk[k16][r];
        if (needm) { int key = kb + k16 * 16 + g * 4 + r; sv = (key > q) ? -1e30f : sv; }
        sc[k16 * 4 + r] = sv;
      }
    // v_max3 tree: 16 -> 6 -> 2 -> 1
    float t0 = fmaxf(fmaxf(sc[0],  sc[1]),  sc[2]);
    float t1 = fmaxf(fmaxf(sc[3],  sc[4]),  sc[5]);
    float t2 = fmaxf(fmaxf(sc[6],  sc[7]),  sc[8]);
    float t3 = fmaxf(fmaxf(sc[9],  sc[10]), sc[11]);
    float t4 = fmaxf(fmaxf(sc[12], sc[13]), sc[14]);
    float u0 = fmaxf(fmaxf(t0, t1), t2);
    float u1 = fmaxf(fmaxf(t3, t4), sc[15]);
    float pmax = fmaxf(u0, u1);
    if (!__all(pmax <= mrun + 8.f)) {            // rescale only when max grows
      float pm = fmaxf(pmax, __shfl_xor(pmax, 16, 64));
      pm = fmaxf(pm, __shfl_xor(pm, 32, 64));
      const float mt = fmaxf(mrun, pm);
      const float scale = EXP2(mrun - mt);
      lrun *= scale;
#pragma unroll
      for (int dt = 0; dt < 4; ++dt) acc[dt] *= scale;
      mrun = mt;
    }
    float pv[16];
#pragma unroll
    for (int i = 0; i < 16; ++i) pv[i] = EXP2(sc[i] - mrun);
    float s8[8], s4[4];
#pragma unroll
    for (int i = 0; i < 8; ++i) s8[i] = pv[i] + pv[i + 8];
#pragma unroll
    for (int i = 0; i < 4; ++i) s4[i] = s8[i] + s8[i + 4];
    lrun += (s4[0] + s4[1]) + (s4[2] + s4[3]);
    bf16x8 pfv[2];
#pragma unroll
    for (int ksub = 0; ksub < 2; ++ksub)
#pragma unroll
      for (int j = 0; j < 4; ++j) {
        pfv[ksub][j]     = (__bf16)pv[ksub * 8 + j];
        pfv[ksub][4 + j] = (__bf16)pv[ksub * 8 + 4 + j];
      }
    // ---- PV: acc^T[d][q] += V^T P (V from LDS) ----
    __builtin_amdgcn_s_setprio(1);
#pragma unroll
    for (int dt = 0; dt < 4; ++dt)
#pragma unroll
      for (int ksub = 0; ksub < 2; ++ksub) {
        bf16x8 vf = *(const bf16x8*)&Vs[cb][dt * 16 + ql][((ksub * 4 + g) ^ m7) * 8];
        acc[dt] = __builtin_amdgcn_mfma_f32_16x16x32_bf16(vf, pfv[ksub], acc[dt], 0, 0, 0);
      }
    __builtin_amdgcn_s_setprio(0);
  }

  float lsum = lrun;
  lsum += __shfl_xor(lsum, 16, 64);
  lsum += __shfl_xor(lsum, 32, 64);
  const float inv = 1.f / lsum;
#pragma unroll
  for (int dt = 0; dt < 4; ++dt) {
    f32x4 o = acc[dt] * inv;
    *(f32x4*)&out[((size_t)b * 2048 + q) * 1024 + h * 64 + dt * 16 + g * 4] = o;
  }
#undef LOADK
}

// ---------------- launch ----------------
extern "C" void kernel_launch(void* const* d_in, const int* in_sizes, int n_in,
                              void* d_out, int out_size, void* d_ws, size_t ws_size,
                              hipStream_t stream) {
  const float* x  = (const float*)d_in[0];
  const float* am = (const float*)d_in[1];
  const float* Wq = (const float*)d_in[2];
  const float* bq = (const float*)d_in[3];
  const float* Aq = (const float*)d_in[4];
  const float* Bq = (const float*)d_in[5];
  const float* Wk = (const float*)d_in[6];
  const float* bk = (const float*)d_in[7];
  const float* Ak = (const float*)d_in[8];
  const float* Bk = (const float*)d_in[9];
  const float* Wv = (const float*)d_in[10];
  const float* bv = (const float*)d_in[11];
  const float* Av = (const float*)d_in[12];
  const float* Bv = (const float*)d_in[13];
  float* out = (float*)d_out;

  u16* xbf   = (u16*)d_ws;                     // 4194304 u16 = 8 MB
  u16* wbf   = xbf + 4194304;                  // 3145728 u16 = 6 MB
  u16* qkv   = wbf + 3145728;                  // 12582912 u16 = 24 MB
  float* mk  = (float*)(qkv + 12582912);       // 4096 f32 = 16 KB (mask*log2e)

  cvt_kernel<<<7172, 256, 0, stream>>>(x, Wq, Wk, Wv, Aq, Ak, Av, Bq, Bk, Bv, am, xbf, wbf, mk);
  qkv_gemm<<<dim3(8, 32, 3), 256, 0, stream>>>(xbf, wbf, bq, bk, bv, qkv);
  attn_kernel<<<1024, 256, 0, stream>>>(qkv, mk, out);
}